// Round 3
// baseline (485.718 us; speedup 1.0000x reference)
//
#include <hip/hip_runtime.h>
#include <hip/hip_bf16.h>
#include <math.h>

#define B_   2
#define S_   2048
#define HID  2048
#define NH   16
#define HD   128

typedef __bf16 bf16_t;
typedef __bf16 bf16x4 __attribute__((ext_vector_type(4)));
typedef __bf16 bf16x8 __attribute__((ext_vector_type(8)));
typedef float  f32x4  __attribute__((ext_vector_type(4)));

__device__ __forceinline__ f32x4 mfma16(bf16x8 a, bf16x8 b, f32x4 c) {
    return __builtin_amdgcn_mfma_f32_16x16x32_bf16(a, b, c, 0, 0, 0);
}

__device__ __forceinline__ void gl2lds16(const void* g, void* l) {
    __builtin_amdgcn_global_load_lds((__attribute__((address_space(1))) void*)(g),
                                     (__attribute__((address_space(3))) void*)(l),
                                     16, 0, 0);
}

// ---------------------------------------------------------------------------
// fp32 -> bf16 conversion of hs + 4 weights (float4 in, bf16x4 out).
// float4 counts (cum): hs 2097152 | Wq 1048576 | Wk 65536 | Wv 65536 | Wo 1048576
// ---------------------------------------------------------------------------
__global__ void convert_bf16(const float* __restrict__ s0, const float* __restrict__ s1,
                             const float* __restrict__ s2, const float* __restrict__ s3,
                             const float* __restrict__ s4,
                             bf16_t* __restrict__ d0, bf16_t* __restrict__ d1,
                             bf16_t* __restrict__ d2, bf16_t* __restrict__ d3,
                             bf16_t* __restrict__ d4)
{
    const size_t stride = (size_t)gridDim.x * blockDim.x;
    for (size_t i = (size_t)blockIdx.x * blockDim.x + threadIdx.x; i < 4325376; i += stride) {
        const float* s; bf16_t* d; size_t off;
        if (i < 2097152)      { s = s0; d = d0; off = i; }
        else if (i < 3145728) { s = s1; d = d1; off = i - 2097152; }
        else if (i < 3211264) { s = s2; d = d2; off = i - 3145728; }
        else if (i < 3276800) { s = s3; d = d3; off = i - 3211264; }
        else                  { s = s4; d = d4; off = i - 3276800; }
        float4 v = ((const float4*)s)[off];
        bf16x4 o;
        o[0] = (bf16_t)v.x; o[1] = (bf16_t)v.y; o[2] = (bf16_t)v.z; o[3] = (bf16_t)v.w;
        ((bf16x4*)d)[off] = o;
    }
}

// ---------------------------------------------------------------------------
// broadcast compact bf16 K/V [b][s][128] -> fp32 key/value_states [b][16][s][128].
// ---------------------------------------------------------------------------
__global__ void broadcast_kv(const bf16_t* __restrict__ k_ws, const bf16_t* __restrict__ v_ws,
                             float* __restrict__ keyo, float* __restrict__ valo)
{
    const size_t stride = (size_t)gridDim.x * blockDim.x;
    for (size_t i = (size_t)blockIdx.x * blockDim.x + threadIdx.x; i < 4194304; i += stride) {
        int which = i >= 2097152;
        size_t f = which ? i - 2097152 : i;
        size_t e = f * 4;                         // < 8388608
        int d = (int)(e & 127);
        size_t s = (e >> 7) & 2047;
        size_t b = e >> 22;                       // 0 or 1
        const bf16_t* src = (which ? v_ws : k_ws) + (b * S_ + s) * HD + d;
        bf16x4 kv = *(const bf16x4*)src;
        float4 o;
        o.x = (float)kv[0]; o.y = (float)kv[1]; o.z = (float)kv[2]; o.w = (float)kv[3];
        *(float4*)((which ? valo : keyo) + e) = o;
    }
}

// ---------------------------------------------------------------------------
// NT GEMM, 128x128 tile, BK=32, 4 waves (2x2 of 64x64), mfma 16x16x32 bf16.
// MODE 0: C = Xb @ [Wq;Wk;Wv]b^T (N=2304): bn<16 -> qb; bn==16 -> k_ws;
//         bn==17 -> v_ws + vt_ws.   MODE 1: C = O @ Wo^T -> fp32 out.
// ---------------------------------------------------------------------------
template <int MODE>
__global__ __launch_bounds__(256, 2)
void gemm_nt(const bf16_t* __restrict__ A,  const bf16_t* __restrict__ B0,
             const bf16_t* __restrict__ B1, const bf16_t* __restrict__ B2,
             bf16_t* __restrict__ q_ws, bf16_t* __restrict__ k_ws,
             bf16_t* __restrict__ v_ws, bf16_t* __restrict__ vt_ws,
             float* __restrict__ outf)
{
    __shared__ __align__(16) ushort sA[128 * 32];
    __shared__ __align__(16) ushort sB[128 * 32];

    const int tid  = threadIdx.x;
    const int lane = tid & 63;
    const int wave = tid >> 6;
    const int quad = lane >> 4;
    const int l16  = lane & 15;
    const int bn = blockIdx.x, bm = blockIdx.y;
    const int wm = (wave & 1) * 64;
    const int wn = (wave >> 1) * 64;

    const bf16_t* Bbase;
    if (MODE == 0) Bbase = (bn < 16) ? (B0 + (size_t)bn * 128 * HID) : (bn == 16 ? B1 : B2);
    else           Bbase = B0 + (size_t)bn * 128 * HID;
    const bf16_t* Abase = A + (size_t)bm * 128 * HID;

    const int c0 = tid, c1 = tid + 256;
    const int r0 = c0 >> 2, o0 = (c0 & 3) * 8;
    const int r1 = c1 >> 2, o1 = (c1 & 3) * 8;

    f32x4 acc[4][4] = {};

    for (int kt = 0; kt < HID / 32; ++kt) {
        const int ko = kt * 32;
        gl2lds16(Abase + (size_t)r0 * HID + ko + o0, sA + c0 * 8);
        gl2lds16(Abase + (size_t)r1 * HID + ko + o1, sA + c1 * 8);
        gl2lds16(Bbase + (size_t)r0 * HID + ko + o0, sB + c0 * 8);
        gl2lds16(Bbase + (size_t)r1 * HID + ko + o1, sB + c1 * 8);
        __syncthreads();

        bf16x8 af[4], bfr[4];
        for (int mt = 0; mt < 4; ++mt)
            af[mt] = *(const bf16x8*)(sA + (wm + mt * 16 + l16) * 32 + quad * 8);
        for (int nt = 0; nt < 4; ++nt)
            bfr[nt] = *(const bf16x8*)(sB + (wn + nt * 16 + l16) * 32 + quad * 8);
        for (int mt = 0; mt < 4; ++mt)
            for (int nt = 0; nt < 4; ++nt)
                acc[mt][nt] = mfma16(af[mt], bfr[nt], acc[mt][nt]);
        __syncthreads();
    }

    for (int mt = 0; mt < 4; ++mt) {
        for (int nt = 0; nt < 4; ++nt) {
            for (int j = 0; j < 4; ++j) {
                float v = acc[mt][nt][j];
                int row = bm * 128 + wm + mt * 16 + quad * 4 + j;
                int col = wn + nt * 16 + l16;
                if (MODE == 1) {
                    outf[(size_t)row * HID + bn * 128 + col] = v;
                } else {
                    bf16_t bv = (bf16_t)v;
                    if (bn < 16) {
                        q_ws[(size_t)row * HID + bn * 128 + col] = bv;
                    } else {
                        int b = row >> 11, s = row & 2047, d = col;
                        if (bn == 16) {
                            k_ws[((size_t)b * S_ + s) * HD + d] = bv;
                        } else {
                            v_ws[((size_t)b * S_ + s) * HD + d] = bv;
                            vt_ws[((size_t)b * HD + d) * S_ + s] = bv;
                        }
                    }
                }
            }
        }
    }
}

// ---------------------------------------------------------------------------
// Flash-style MQA attention, round 3.
// Block = 256 threads (4 waves) x 128-row q-tile; wave owns 32 rows (mt=2,
// restoring round-0's 64 MFMA : 36 ds_read_b128 amortization). Grid (16,32)
// = 512 blocks = 2 blocks/CU (LDS 37.1 KB x2 = 74.2 KB): two independent
// barrier domains per CU so one block's MFMA overlaps the other's
// softmax/staging phases. T14 async-STAGE: next K/V tile global->reg loads
// issued after softmax (hidden under PV), ds_write after top barrier.
// Softmax in exp2 domain with deferred-max (THR=8 -> P bounded by 256).
// ---------------------------------------------------------------------------
#define SV_U 9216    // ushort offset of sV (region1 = sP 4x32x72 >= sK 64x136)
#define SM_U 18432   // ushort offset of mask floats

__global__ __launch_bounds__(256, 2)
void attn_kernel(const bf16_t* __restrict__ Qw, const bf16_t* __restrict__ Kc,
                 const bf16_t* __restrict__ Vt, const float* __restrict__ mask,
                 bf16_t* __restrict__ Ow)
{
    __shared__ __align__(16) ushort smem[18560];
    float* sMask = (float*)&smem[SM_U];

    const int tid  = threadIdx.x;
    const int lane = tid & 63;
    const int wave = tid >> 6;     // 0..3
    const int quad = lane >> 4;
    const int l16  = lane & 15;
    const int qt = blockIdx.x;     // 0..15 (128-row q-tiles)
    const int bh = blockIdx.y;     // 0..31
    const int b = bh >> 4, h = bh & 15;

    // per-thread staging geometry (K: [64][128] -> stride 136; V^T: [128][64] -> stride 72)
    int koff[4], voff[4], klds[4], vlds[4];
#pragma unroll
    for (int i = 0; i < 4; ++i) {
        int c = tid + i * 256;                    // 0..1023
        koff[i] = (c >> 4) * HD + (c & 15) * 8;
        klds[i] = (c >> 4) * 136 + (c & 15) * 8;
        voff[i] = (c >> 3) * S_ + (c & 7) * 8;
        vlds[i] = SV_U + (c >> 3) * 72 + (c & 7) * 8;
    }

    const bf16_t* kg = Kc + (size_t)b * S_ * HD;
    const bf16_t* vg = Vt + (size_t)b * HD * S_;

    // ---- Q fragments: direct global -> registers ----
    bf16x8 qf[2][4];
    {
        const bf16_t* qg = Qw + ((size_t)(b * S_ + qt * 128 + wave * 32)) * HID + h * HD;
#pragma unroll
        for (int mt = 0; mt < 2; ++mt)
#pragma unroll
            for (int kk = 0; kk < 4; ++kk)
                qf[mt][kk] = *(const bf16x8*)(qg + (size_t)(mt * 16 + l16) * HID + kk * 32 + quad * 8);
    }

    f32x4 oa[2][8] = {};
    float mrow[2][4], lrow[2][4];
#pragma unroll
    for (int mt = 0; mt < 2; ++mt)
#pragma unroll
        for (int j = 0; j < 4; ++j) { mrow[mt][j] = -INFINITY; lrow[mt][j] = 0.f; }

    const float scale2 = 0.08838834764831845f * 1.4426950408889634f;  // /sqrt(128) * log2(e)
    const float NEGF   = -3.4028234663852886e38f;
    const float LOG2E  = 1.4426950408889634f;

    // ---- prologue: prefetch tile 0 into registers (T14) ----
    uint4 kreg[4], vreg[4];
    float mreg = 1.0f;
#pragma unroll
    for (int i = 0; i < 4; ++i) {
        kreg[i] = *(const uint4*)(kg + koff[i]);
        vreg[i] = *(const uint4*)(vg + voff[i]);
    }
    if (tid < 64) mreg = mask[b * S_ + tid];

    for (int kt = 0; kt < S_ / 64; ++kt) {
        __syncthreads();   // prev iter's sP(pf)/sV(vf) reads done before restaging
#pragma unroll
        for (int i = 0; i < 4; ++i) {
            *(uint4*)(&smem[klds[i]]) = kreg[i];
            *(uint4*)(&smem[vlds[i]]) = vreg[i];
        }
        if (tid < 64) sMask[tid] = (1.0f - mreg) * NEGF * LOG2E;
        __syncthreads();

        // ---- S = (Q K^T) * scale2 + maskadd (log2 domain); kk-outer for ILP ----
        f32x4 sa[2][4] = {};
#pragma unroll
        for (int kk = 0; kk < 4; ++kk)
#pragma unroll
            for (int nt = 0; nt < 4; ++nt) {
                bf16x8 kf = *(const bf16x8*)(&smem[(nt * 16 + l16) * 136 + kk * 32 + quad * 8]);
#pragma unroll
                for (int mt = 0; mt < 2; ++mt)
                    sa[mt][nt] = mfma16(qf[mt][kk], kf, sa[mt][nt]);
            }
#pragma unroll
        for (int nt = 0; nt < 4; ++nt) {
            float madd = sMask[nt * 16 + l16];
#pragma unroll
            for (int mt = 0; mt < 2; ++mt)
#pragma unroll
                for (int j = 0; j < 4; ++j)
                    sa[mt][nt][j] = sa[mt][nt][j] * scale2 + madd;
        }
        __syncthreads();   // all kf reads done before sP overlays sK region

        // ---- online softmax (exp2 domain, deferred-max); P -> sP ----
        float rm[2][4];
#pragma unroll
        for (int mt = 0; mt < 2; ++mt)
#pragma unroll
            for (int j = 0; j < 4; ++j) {
                float m = sa[mt][0][j];
                for (int nt = 1; nt < 4; ++nt) m = fmaxf(m, sa[mt][nt][j]);
                rm[mt][j] = m;
            }
        for (int off = 1; off < 16; off <<= 1)
#pragma unroll
            for (int mt = 0; mt < 2; ++mt)
#pragma unroll
                for (int j = 0; j < 4; ++j)
                    rm[mt][j] = fmaxf(rm[mt][j], __shfl_xor(rm[mt][j], off));
        bool need = false;
#pragma unroll
        for (int mt = 0; mt < 2; ++mt)
#pragma unroll
            for (int j = 0; j < 4; ++j)
                need = need || (rm[mt][j] > mrow[mt][j] + 8.0f);
        if (__any((int)need)) {
#pragma unroll
            for (int mt = 0; mt < 2; ++mt)
#pragma unroll
                for (int j = 0; j < 4; ++j) {
                    float mnew  = fmaxf(mrow[mt][j], rm[mt][j]);
                    float alpha = exp2f(mrow[mt][j] - mnew);
                    mrow[mt][j] = mnew;
                    lrow[mt][j] *= alpha;
                    for (int nt = 0; nt < 8; ++nt) oa[mt][nt][j] *= alpha;
                }
        }
        bf16_t* sPp = (bf16_t*)&smem[wave * 2304];
#pragma unroll
        for (int mt = 0; mt < 2; ++mt) {
            float rs[4] = {0.f, 0.f, 0.f, 0.f};
#pragma unroll
            for (int nt = 0; nt < 4; ++nt)
#pragma unroll
                for (int j = 0; j < 4; ++j) {
                    float p = exp2f(sa[mt][nt][j] - mrow[mt][j]);
                    rs[j] += p;
                    sPp[(mt * 16 + quad * 4 + j) * 72 + nt * 16 + l16] = (bf16_t)p;
                }
            for (int off = 1; off < 16; off <<= 1)
#pragma unroll
                for (int j = 0; j < 4; ++j) rs[j] += __shfl_xor(rs[j], off);
#pragma unroll
            for (int j = 0; j < 4; ++j) lrow[mt][j] += rs[j];
        }

        // ---- T14: issue next tile's global loads; latency hides under PV ----
        if (kt + 1 < S_ / 64) {
            const bf16_t* kgn = kg + (size_t)(kt + 1) * 64 * HD;
            const bf16_t* vgn = vg + (kt + 1) * 64;
#pragma unroll
            for (int i = 0; i < 4; ++i) {
                kreg[i] = *(const uint4*)(kgn + koff[i]);
                vreg[i] = *(const uint4*)(vgn + voff[i]);
            }
            if (tid < 64) mreg = mask[b * S_ + (kt + 1) * 64 + tid];
        }

        // ---- O += P V  (pf: wave-private sP rows; same-wave write->read) ----
        bf16x8 pf[2][2];
#pragma unroll
        for (int mt = 0; mt < 2; ++mt)
#pragma unroll
            for (int kk = 0; kk < 2; ++kk)
                pf[mt][kk] = *(const bf16x8*)(&smem[wave * 2304 + (mt * 16 + l16) * 72 + kk * 32 + quad * 8]);
#pragma unroll
        for (int kk = 0; kk < 2; ++kk)
#pragma unroll
            for (int nt = 0; nt < 8; ++nt) {
                bf16x8 vf = *(const bf16x8*)(&smem[SV_U + (nt * 16 + l16) * 72 + kk * 32 + quad * 8]);
#pragma unroll
                for (int mt = 0; mt < 2; ++mt)
                    oa[mt][nt] = mfma16(pf[mt][kk], vf, oa[mt][nt]);
            }
    }

    // ---- epilogue: O /= l, write [b,s,h*128+d] ----
#pragma unroll
    for (int mt = 0; mt < 2; ++mt)
#pragma unroll
        for (int j = 0; j < 4; ++j) {
            float inv = 1.0f / lrow[mt][j];
            int s = qt * 128 + wave * 32 + mt * 16 + quad * 4 + j;
            for (int nt = 0; nt < 8; ++nt) {
                int d = nt * 16 + l16;
                Ow[((size_t)(b * S_ + s)) * HID + h * HD + d] = (bf16_t)(oa[mt][nt][j] * inv);
            }
        }
}

// ---------------------------------------------------------------------------
// Scratch overlay inside d_out (all regions phase-disjoint):
//   O1 = out[0 : 8388608)          : wqb/wkb/wvb bf16 -> final out (gemm1)
//   O2 = out[8388608 : 16777216)   : qb bf16 | wob bf16 -> final key (bcast)
//   O3 = out[16777216 : 25165824)  : hsb bf16, then o_ws (alias) -> final value (bcast)
// d_ws: k_ws/v_ws/vt_ws bf16 = 3 MB only.
// Order: convert -> gemm0 -> attn -> gemm1 -> broadcast_kv (last).
// ---------------------------------------------------------------------------
extern "C" void kernel_launch(void* const* d_in, const int* in_sizes, int n_in,
                              void* d_out, int out_size, void* d_ws, size_t ws_size,
                              hipStream_t stream) {
    const float* hs   = (const float*)d_in[0];
    const float* mask = (const float*)d_in[1];
    const float* Wq   = (const float*)d_in[2];
    const float* Wk   = (const float*)d_in[3];
    const float* Wv   = (const float*)d_in[4];
    const float* Wo   = (const float*)d_in[5];
    float* out = (float*)d_out;

    bf16_t* wqb = (bf16_t*)out;                         // O1
    bf16_t* wkb = wqb + 4194304;
    bf16_t* wvb = wkb + 262144;
    bf16_t* qb  = (bf16_t*)(out + 8388608);             // O2
    bf16_t* wob = (bf16_t*)(out + 12582912);            // O2 tail
    bf16_t* hsb = (bf16_t*)(out + 16777216);            // O3
    bf16_t* o_ws = hsb;                                 // alias (hsb dead after gemm0)

    bf16_t* k_ws  = (bf16_t*)d_ws;                      // 524,288 bf16
    bf16_t* v_ws  = k_ws + 524288;
    bf16_t* vt_ws = v_ws + 524288;                      // total 3 MB

    // 1) fp32 -> bf16 staging
    convert_bf16<<<2048, 256, 0, stream>>>(hs, Wq, Wk, Wv, Wo, hsb, wqb, wkb, wvb, wob);
    // 2) QKV projection: Q->qb (O2), K->k_ws, V->v_ws + vt_ws
    gemm_nt<0><<<dim3(18, 32), 256, 0, stream>>>(hsb, wqb, wkb, wvb, qb, k_ws, v_ws, vt_ws, nullptr);
    // 3) flash MQA attention -> o_ws (O3, overwrites dead hsb)
    attn_kernel<<<dim3(16, 32), 256, 0, stream>>>(qb, k_ws, vt_ws, mask, o_ws);
    // 4) output projection -> fp32 out (O1, overwrites dead wq/wk/wv)
    gemm_nt<1><<<dim3(16, 32), 256, 0, stream>>>(o_ws, wob, nullptr, nullptr, nullptr, nullptr, nullptr, nullptr, out);
    // 5) key/value broadcast -> O2/O3 (overwrites dead qb/wob/o_ws)
    broadcast_kv<<<4096, 256, 0, stream>>>(k_ws, v_ws, out + 8388608, out + 16777216);
}

// Round 4
// 415.237 us; speedup vs baseline: 1.1697x; 1.1697x over previous
//
#include <hip/hip_runtime.h>
#include <hip/hip_bf16.h>
#include <math.h>

#define B_   2
#define S_   2048
#define HID  2048
#define NH   16
#define HD   128

typedef __bf16 bf16_t;
typedef __bf16 bf16x4 __attribute__((ext_vector_type(4)));
typedef __bf16 bf16x8 __attribute__((ext_vector_type(8)));
typedef float  f32x4  __attribute__((ext_vector_type(4)));

__device__ __forceinline__ f32x4 mfma16(bf16x8 a, bf16x8 b, f32x4 c) {
    return __builtin_amdgcn_mfma_f32_16x16x32_bf16(a, b, c, 0, 0, 0);
}

__device__ __forceinline__ void gl2lds16(const void* g, void* l) {
    __builtin_amdgcn_global_load_lds((__attribute__((address_space(1))) void*)(g),
                                     (__attribute__((address_space(3))) void*)(l),
                                     16, 0, 0);
}

// ---------------------------------------------------------------------------
// fp32 -> bf16 conversion of hs + 4 weights (float4 in, bf16x4 out).
// ---------------------------------------------------------------------------
__global__ void convert_bf16(const float* __restrict__ s0, const float* __restrict__ s1,
                             const float* __restrict__ s2, const float* __restrict__ s3,
                             const float* __restrict__ s4,
                             bf16_t* __restrict__ d0, bf16_t* __restrict__ d1,
                             bf16_t* __restrict__ d2, bf16_t* __restrict__ d3,
                             bf16_t* __restrict__ d4)
{
    const size_t stride = (size_t)gridDim.x * blockDim.x;
    for (size_t i = (size_t)blockIdx.x * blockDim.x + threadIdx.x; i < 4325376; i += stride) {
        const float* s; bf16_t* d; size_t off;
        if (i < 2097152)      { s = s0; d = d0; off = i; }
        else if (i < 3145728) { s = s1; d = d1; off = i - 2097152; }
        else if (i < 3211264) { s = s2; d = d2; off = i - 3145728; }
        else if (i < 3276800) { s = s3; d = d3; off = i - 3211264; }
        else                  { s = s4; d = d4; off = i - 3276800; }
        float4 v = ((const float4*)s)[off];
        bf16x4 o;
        o[0] = (bf16_t)v.x; o[1] = (bf16_t)v.y; o[2] = (bf16_t)v.z; o[3] = (bf16_t)v.w;
        ((bf16x4*)d)[off] = o;
    }
}

// ---------------------------------------------------------------------------
// broadcast compact bf16 K/V [b][s][128] -> fp32 key/value_states [b][16][s][128].
// ---------------------------------------------------------------------------
__global__ void broadcast_kv(const bf16_t* __restrict__ k_ws, const bf16_t* __restrict__ v_ws,
                             float* __restrict__ keyo, float* __restrict__ valo)
{
    const size_t stride = (size_t)gridDim.x * blockDim.x;
    for (size_t i = (size_t)blockIdx.x * blockDim.x + threadIdx.x; i < 4194304; i += stride) {
        int which = i >= 2097152;
        size_t f = which ? i - 2097152 : i;
        size_t e = f * 4;                         // < 8388608
        int d = (int)(e & 127);
        size_t s = (e >> 7) & 2047;
        size_t b = e >> 22;                       // 0 or 1
        const bf16_t* src = (which ? v_ws : k_ws) + (b * S_ + s) * HD + d;
        bf16x4 kv = *(const bf16x4*)src;
        float4 o;
        o.x = (float)kv[0]; o.y = (float)kv[1]; o.z = (float)kv[2]; o.w = (float)kv[3];
        *(float4*)((which ? valo : keyo) + e) = o;
    }
}

// ---------------------------------------------------------------------------
// NT GEMM, 128x128 tile, BK=32, 4 waves (2x2 of 64x64), mfma 16x16x32 bf16.
// MODE 0: C = Xb @ [Wq;Wk;Wv]b^T (N=2304): bn<16 -> qb; bn==16 -> k_ws;
//         bn==17 -> v_ws + vt_ws.   MODE 1: C = O @ Wo^T -> fp32 out.
// ---------------------------------------------------------------------------
template <int MODE>
__global__ __launch_bounds__(256, 2)
void gemm_nt(const bf16_t* __restrict__ A,  const bf16_t* __restrict__ B0,
             const bf16_t* __restrict__ B1, const bf16_t* __restrict__ B2,
             bf16_t* __restrict__ q_ws, bf16_t* __restrict__ k_ws,
             bf16_t* __restrict__ v_ws, bf16_t* __restrict__ vt_ws,
             float* __restrict__ outf)
{
    __shared__ __align__(16) ushort sA[128 * 32];
    __shared__ __align__(16) ushort sB[128 * 32];

    const int tid  = threadIdx.x;
    const int lane = tid & 63;
    const int wave = tid >> 6;
    const int quad = lane >> 4;
    const int l16  = lane & 15;
    const int bn = blockIdx.x, bm = blockIdx.y;
    const int wm = (wave & 1) * 64;
    const int wn = (wave >> 1) * 64;

    const bf16_t* Bbase;
    if (MODE == 0) Bbase = (bn < 16) ? (B0 + (size_t)bn * 128 * HID) : (bn == 16 ? B1 : B2);
    else           Bbase = B0 + (size_t)bn * 128 * HID;
    const bf16_t* Abase = A + (size_t)bm * 128 * HID;

    const int c0 = tid, c1 = tid + 256;
    const int r0 = c0 >> 2, o0 = (c0 & 3) * 8;
    const int r1 = c1 >> 2, o1 = (c1 & 3) * 8;

    f32x4 acc[4][4] = {};

    for (int kt = 0; kt < HID / 32; ++kt) {
        const int ko = kt * 32;
        gl2lds16(Abase + (size_t)r0 * HID + ko + o0, sA + c0 * 8);
        gl2lds16(Abase + (size_t)r1 * HID + ko + o1, sA + c1 * 8);
        gl2lds16(Bbase + (size_t)r0 * HID + ko + o0, sB + c0 * 8);
        gl2lds16(Bbase + (size_t)r1 * HID + ko + o1, sB + c1 * 8);
        __syncthreads();

        bf16x8 af[4], bfr[4];
        for (int mt = 0; mt < 4; ++mt)
            af[mt] = *(const bf16x8*)(sA + (wm + mt * 16 + l16) * 32 + quad * 8);
        for (int nt = 0; nt < 4; ++nt)
            bfr[nt] = *(const bf16x8*)(sB + (wn + nt * 16 + l16) * 32 + quad * 8);
        for (int mt = 0; mt < 4; ++mt)
            for (int nt = 0; nt < 4; ++nt)
                acc[mt][nt] = mfma16(af[mt], bfr[nt], acc[mt][nt]);
        __syncthreads();
    }

    for (int mt = 0; mt < 4; ++mt) {
        for (int nt = 0; nt < 4; ++nt) {
            for (int j = 0; j < 4; ++j) {
                float v = acc[mt][nt][j];
                int row = bm * 128 + wm + mt * 16 + quad * 4 + j;
                int col = wn + nt * 16 + l16;
                if (MODE == 1) {
                    outf[(size_t)row * HID + bn * 128 + col] = v;
                } else {
                    bf16_t bv = (bf16_t)v;
                    if (bn < 16) {
                        q_ws[(size_t)row * HID + bn * 128 + col] = bv;
                    } else {
                        int b = row >> 11, s = row & 2047, d = col;
                        if (bn == 16) {
                            k_ws[((size_t)b * S_ + s) * HD + d] = bv;
                        } else {
                            v_ws[((size_t)b * S_ + s) * HD + d] = bv;
                            vt_ws[((size_t)b * HD + d) * S_ + s] = bv;
                        }
                    }
                }
            }
        }
    }
}

// ---------------------------------------------------------------------------
// Flash-style MQA attention, round 4: round-3 structure WITHOUT the
// cross-phase register prefetch (it spilled: WRITE_SIZE 16->240 MB).
// Block = 256 threads (4 waves) x 128-row q-tile; wave owns 32 rows (mt=2,
// round-0's 64 MFMA : 36 ds_read amortization). Grid (16,32) = 512 blocks
// = 2 blocks/CU (LDS 37.1 KB x2): two independent barrier domains per CU.
// K/V staged inline between barriers (transient regs only). Softmax in
// exp2 domain with deferred-max (THR=8). All oa-touching loops unrolled.
// ---------------------------------------------------------------------------
#define SV_U 9216    // ushort offset of sV (region1 = sP 4x32x72 >= sK 64x136)
#define SM_U 18432   // ushort offset of mask floats

__global__ __launch_bounds__(256, 2)
void attn_kernel(const bf16_t* __restrict__ Qw, const bf16_t* __restrict__ Kc,
                 const bf16_t* __restrict__ Vt, const float* __restrict__ mask,
                 bf16_t* __restrict__ Ow)
{
    __shared__ __align__(16) ushort smem[18560];
    float* sMask = (float*)&smem[SM_U];

    const int tid  = threadIdx.x;
    const int lane = tid & 63;
    const int wave = tid >> 6;     // 0..3
    const int quad = lane >> 4;
    const int l16  = lane & 15;
    const int qt = blockIdx.x;     // 0..15 (128-row q-tiles)
    const int bh = blockIdx.y;     // 0..31
    const int b = bh >> 4, h = bh & 15;

    const bf16_t* kg = Kc + (size_t)b * S_ * HD;
    const bf16_t* vg = Vt + (size_t)b * HD * S_;

    // ---- Q fragments: direct global -> registers ----
    bf16x8 qf[2][4];
    {
        const bf16_t* qg = Qw + ((size_t)(b * S_ + qt * 128 + wave * 32)) * HID + h * HD;
#pragma unroll
        for (int mt = 0; mt < 2; ++mt)
#pragma unroll
            for (int kk = 0; kk < 4; ++kk)
                qf[mt][kk] = *(const bf16x8*)(qg + (size_t)(mt * 16 + l16) * HID + kk * 32 + quad * 8);
    }

    f32x4 oa[2][8] = {};
    float mrow[2][4], lrow[2][4];
#pragma unroll
    for (int mt = 0; mt < 2; ++mt)
#pragma unroll
        for (int j = 0; j < 4; ++j) { mrow[mt][j] = -INFINITY; lrow[mt][j] = 0.f; }

    const float scale2 = 0.08838834764831845f * 1.4426950408889634f;  // /sqrt(128) * log2(e)
    const float NEGF   = -3.4028234663852886e38f;
    const float LOG2E  = 1.4426950408889634f;

    for (int kt = 0; kt < S_ / 64; ++kt) {
        __syncthreads();   // prev iter's sP(pf)/sV(vf) reads done before restaging
        // ---- inline staging: K [64][128]->stride 136, V^T [128][64]->stride 72 ----
        {
            uint4 kr[4], vr[4];
#pragma unroll
            for (int i = 0; i < 4; ++i) {
                int c = tid + i * 256;                    // 0..1023
                kr[i] = *(const uint4*)(kg + (size_t)(kt * 64 + (c >> 4)) * HD + (c & 15) * 8);
                vr[i] = *(const uint4*)(vg + (size_t)(c >> 3) * S_ + kt * 64 + (c & 7) * 8);
            }
#pragma unroll
            for (int i = 0; i < 4; ++i) {
                int c = tid + i * 256;
                *(uint4*)(&smem[(c >> 4) * 136 + (c & 15) * 8]) = kr[i];
                *(uint4*)(&smem[SV_U + (c >> 3) * 72 + (c & 7) * 8]) = vr[i];
            }
        }
        if (tid < 64) {
            float mv = mask[b * S_ + kt * 64 + tid];
            sMask[tid] = (1.0f - mv) * NEGF * LOG2E;
        }
        __syncthreads();

        // ---- S = (Q K^T) * scale2 + maskadd (log2 domain); kk-outer for ILP ----
        f32x4 sa[2][4] = {};
#pragma unroll
        for (int kk = 0; kk < 4; ++kk)
#pragma unroll
            for (int nt = 0; nt < 4; ++nt) {
                bf16x8 kf = *(const bf16x8*)(&smem[(nt * 16 + l16) * 136 + kk * 32 + quad * 8]);
#pragma unroll
                for (int mt = 0; mt < 2; ++mt)
                    sa[mt][nt] = mfma16(qf[mt][kk], kf, sa[mt][nt]);
            }
#pragma unroll
        for (int nt = 0; nt < 4; ++nt) {
            float madd = sMask[nt * 16 + l16];
#pragma unroll
            for (int mt = 0; mt < 2; ++mt)
#pragma unroll
                for (int j = 0; j < 4; ++j)
                    sa[mt][nt][j] = sa[mt][nt][j] * scale2 + madd;
        }
        __syncthreads();   // all kf reads done before sP overlays sK region

        // ---- online softmax (exp2 domain, deferred-max); P -> sP ----
        float rm[2][4];
#pragma unroll
        for (int mt = 0; mt < 2; ++mt)
#pragma unroll
            for (int j = 0; j < 4; ++j) {
                float m = sa[mt][0][j];
#pragma unroll
                for (int nt = 1; nt < 4; ++nt) m = fmaxf(m, sa[mt][nt][j]);
                rm[mt][j] = m;
            }
#pragma unroll
        for (int off = 1; off < 16; off <<= 1)
#pragma unroll
            for (int mt = 0; mt < 2; ++mt)
#pragma unroll
                for (int j = 0; j < 4; ++j)
                    rm[mt][j] = fmaxf(rm[mt][j], __shfl_xor(rm[mt][j], off));
        bool need = false;
#pragma unroll
        for (int mt = 0; mt < 2; ++mt)
#pragma unroll
            for (int j = 0; j < 4; ++j)
                need = need || (rm[mt][j] > mrow[mt][j] + 8.0f);
        if (__any((int)need)) {
#pragma unroll
            for (int mt = 0; mt < 2; ++mt)
#pragma unroll
                for (int j = 0; j < 4; ++j) {
                    float mnew  = fmaxf(mrow[mt][j], rm[mt][j]);
                    float alpha = exp2f(mrow[mt][j] - mnew);
                    mrow[mt][j] = mnew;
                    lrow[mt][j] *= alpha;
#pragma unroll
                    for (int nt = 0; nt < 8; ++nt) oa[mt][nt][j] *= alpha;
                }
        }
        bf16_t* sPp = (bf16_t*)&smem[wave * 2304];
#pragma unroll
        for (int mt = 0; mt < 2; ++mt) {
            float rs[4] = {0.f, 0.f, 0.f, 0.f};
#pragma unroll
            for (int nt = 0; nt < 4; ++nt)
#pragma unroll
                for (int j = 0; j < 4; ++j) {
                    float p = exp2f(sa[mt][nt][j] - mrow[mt][j]);
                    rs[j] += p;
                    sPp[(mt * 16 + quad * 4 + j) * 72 + nt * 16 + l16] = (bf16_t)p;
                }
#pragma unroll
            for (int off = 1; off < 16; off <<= 1)
#pragma unroll
                for (int j = 0; j < 4; ++j) rs[j] += __shfl_xor(rs[j], off);
#pragma unroll
            for (int j = 0; j < 4; ++j) lrow[mt][j] += rs[j];
        }

        // ---- O += P V  (pf: wave-private sP rows; same-wave write->read) ----
        bf16x8 pf[2][2];
#pragma unroll
        for (int mt = 0; mt < 2; ++mt)
#pragma unroll
            for (int kk = 0; kk < 2; ++kk)
                pf[mt][kk] = *(const bf16x8*)(&smem[wave * 2304 + (mt * 16 + l16) * 72 + kk * 32 + quad * 8]);
#pragma unroll
        for (int kk = 0; kk < 2; ++kk)
#pragma unroll
            for (int nt = 0; nt < 8; ++nt) {
                bf16x8 vf = *(const bf16x8*)(&smem[SV_U + (nt * 16 + l16) * 72 + kk * 32 + quad * 8]);
#pragma unroll
                for (int mt = 0; mt < 2; ++mt)
                    oa[mt][nt] = mfma16(pf[mt][kk], vf, oa[mt][nt]);
            }
    }

    // ---- epilogue: O /= l, write [b,s,h*128+d] ----
#pragma unroll
    for (int mt = 0; mt < 2; ++mt)
#pragma unroll
        for (int j = 0; j < 4; ++j) {
            float inv = 1.0f / lrow[mt][j];
            int s = qt * 128 + wave * 32 + mt * 16 + quad * 4 + j;
#pragma unroll
            for (int nt = 0; nt < 8; ++nt) {
                int d = nt * 16 + l16;
                Ow[((size_t)(b * S_ + s)) * HID + h * HD + d] = (bf16_t)(oa[mt][nt][j] * inv);
            }
        }
}

// ---------------------------------------------------------------------------
// Scratch overlay inside d_out (all regions phase-disjoint):
//   O1 = out[0 : 8388608)          : wqb/wkb/wvb bf16 -> final out (gemm1)
//   O2 = out[8388608 : 16777216)   : qb bf16 | wob bf16 -> final key (bcast)
//   O3 = out[16777216 : 25165824)  : hsb bf16, then o_ws (alias) -> final value (bcast)
// d_ws: k_ws/v_ws/vt_ws bf16 = 3 MB only.
// Order: convert -> gemm0 -> attn -> gemm1 -> broadcast_kv (last).
// ---------------------------------------------------------------------------
extern "C" void kernel_launch(void* const* d_in, const int* in_sizes, int n_in,
                              void* d_out, int out_size, void* d_ws, size_t ws_size,
                              hipStream_t stream) {
    const float* hs   = (const float*)d_in[0];
    const float* mask = (const float*)d_in[1];
    const float* Wq   = (const float*)d_in[2];
    const float* Wk   = (const float*)d_in[3];
    const float* Wv   = (const float*)d_in[4];
    const float* Wo   = (const float*)d_in[5];
    float* out = (float*)d_out;

    bf16_t* wqb = (bf16_t*)out;                         // O1
    bf16_t* wkb = wqb + 4194304;
    bf16_t* wvb = wkb + 262144;
    bf16_t* qb  = (bf16_t*)(out + 8388608);             // O2
    bf16_t* wob = (bf16_t*)(out + 12582912);            // O2 tail
    bf16_t* hsb = (bf16_t*)(out + 16777216);            // O3
    bf16_t* o_ws = hsb;                                 // alias (hsb dead after gemm0)

    bf16_t* k_ws  = (bf16_t*)d_ws;                      // 524,288 bf16
    bf16_t* v_ws  = k_ws + 524288;
    bf16_t* vt_ws = v_ws + 524288;                      // total 3 MB

    // 1) fp32 -> bf16 staging
    convert_bf16<<<2048, 256, 0, stream>>>(hs, Wq, Wk, Wv, Wo, hsb, wqb, wkb, wvb, wob);
    // 2) QKV projection: Q->qb (O2), K->k_ws, V->v_ws + vt_ws
    gemm_nt<0><<<dim3(18, 32), 256, 0, stream>>>(hsb, wqb, wkb, wvb, qb, k_ws, v_ws, vt_ws, nullptr);
    // 3) flash MQA attention -> o_ws (O3, overwrites dead hsb)
    attn_kernel<<<dim3(16, 32), 256, 0, stream>>>(qb, k_ws, vt_ws, mask, o_ws);
    // 4) output projection -> fp32 out (O1, overwrites dead wq/wk/wv)
    gemm_nt<1><<<dim3(16, 32), 256, 0, stream>>>(o_ws, wob, nullptr, nullptr, nullptr, nullptr, nullptr, nullptr, out);
    // 5) key/value broadcast -> O2/O3 (overwrites dead qb/wob/o_ws)
    broadcast_kv<<<4096, 256, 0, stream>>>(k_ws, v_ws, out + 8388608, out + 16777216);
}